// Round 4
// baseline (610.580 us; speedup 1.0000x reference)
//
#include <hip/hip_runtime.h>
#include <stdint.h>

#define BATCH 4096
#define DIM   1024
#define PPREV 8

// ============================================================================
// Wave (64-lane) helpers
// ============================================================================
__device__ __forceinline__ int wave_max_i32(int v) {
    #pragma unroll
    for (int m = 1; m < 64; m <<= 1) v = max(v, __shfl_xor(v, m));
    return v;
}
__device__ __forceinline__ int wave_min_i32(int v) {
    #pragma unroll
    for (int m = 1; m < 64; m <<= 1) v = min(v, __shfl_xor(v, m));
    return v;
}
// popcount of mask over lanes strictly below the current lane
__device__ __forceinline__ int lt_count(unsigned long long m) {
    return __builtin_amdgcn_mbcnt_hi((unsigned)(m >> 32),
           __builtin_amdgcn_mbcnt_lo((unsigned)m, 0));
}

// ============================================================================
// Top-10 by |value|, exact jax.lax.top_k tie-break (lowest flat index wins
// among equal values). Element j of the row lives in lane (j>>4), slot (j&15).
// Key = |f32 bits| as int; payload = ((1023-j)<<1)|sign, so (key,pay)
// lexicographic-descending == (value desc, index asc).
// ============================================================================

// Always-correct fallback: 10 wave-argmax rounds over all 1024 elements.
__device__ __forceinline__ void top10_full(const int kin[16], int sgn, int lane,
                                           int wi[10], float wv[10]) {
    int k[16];
    #pragma unroll
    for (int s = 0; s < 16; ++s) k[s] = kin[s];
    #pragma unroll
    for (int r = 0; r < 10; ++r) {
        int lm = k[0]; int ls = 0;
        #pragma unroll
        for (int s = 1; s < 16; ++s) { if (k[s] > lm) { lm = k[s]; ls = s; } }
        int m = wave_max_i32(lm);
        int cj = (lm == m) ? ((lane << 4) | ls) : 4096;
        int jw = wave_min_i32(cj);
        int wl = jw >> 4, ws = jw & 15;
        int sg = __shfl(sgn, wl);
        wi[r] = jw;
        wv[r] = __int_as_float(m | (((sg >> ws) & 1) << 31));
        if (lane == wl) {
            #pragma unroll
            for (int s = 0; s < 16; ++s) if (s == ws) k[s] = 0;
        }
    }
}

template<bool SEEDED>
__device__ __forceinline__ void select10(const float cz[16], int lane,
                                         int2* s_cand, int2* s_win,
                                         int& tbits, int wi[10], float wv[10]) {
    int k[16]; int sgn = 0;
    #pragma unroll
    for (int s = 0; s < 16; ++s) {
        int bb = __float_as_int(cz[s]);
        k[s] = bb & 0x7fffffff;
        sgn |= (int)(((unsigned)bb >> 31) << s);
    }

    if (!SEEDED) {
        // valid lower bound for the 10th-largest: 10th-largest of the 64
        // per-lane maxima (10 distinct lanes each hold an element >= it).
        int lm = k[0];
        #pragma unroll
        for (int s = 1; s < 16; ++s) lm = max(lm, k[s]);
        #pragma unroll
        for (int k2 = 2; k2 <= 64; k2 <<= 1) {
            #pragma unroll
            for (int j = k2 >> 1; j > 0; j >>= 1) {
                int p = __shfl_xor(lm, j);
                bool keep_max = (((lane & k2) == 0) == ((lane & j) == 0));
                if ((p > lm) == keep_max) lm = p;
            }
        }
        tbits = __builtin_amdgcn_readlane(lm, 9);
    }

    // relax threshold until >= 10 candidates (ballot-count only)
    int tb = tbits;
    int total;
    #pragma unroll 1
    for (;;) {
        total = 0;
        #pragma unroll
        for (int s = 0; s < 16; ++s)
            total += __popcll(__ballot(k[s] >= tb));
        if (total >= 10) break;
        tb = (tb > 0x00800000) ? (tb - 0x00800000) : 0;
    }

    if (total <= 64) {
        // compact candidates into per-wave LDS (unordered)
        int base = 0;
        #pragma unroll
        for (int s = 0; s < 16; ++s) {
            unsigned long long bs = __ballot(k[s] >= tb);
            if (k[s] >= tb) {
                int pos = base + lt_count(bs);
                s_cand[pos] = make_int2(k[s], ((1023 - ((lane << 4) | s)) << 1) | ((sgn >> s) & 1));
            }
            base += __popcll(bs);
        }
        asm volatile("s_waitcnt lgkmcnt(0)" ::: "memory");
        // own candidate
        int kb = -1, pay = 0;
        if (lane < total) { int2 c = s_cand[lane]; kb = c.x; pay = c.y; }
        // exact rank by broadcast reads (4x unrolled so loads pipeline)
        int rank = 0;
        int e = 0;
        #pragma unroll 1
        for (; e + 4 <= total; e += 4) {
            int2 c0 = s_cand[e], c1 = s_cand[e+1], c2 = s_cand[e+2], c3 = s_cand[e+3];
            rank += ((c0.x > kb) || (c0.x == kb && c0.y > pay)) ? 1 : 0;
            rank += ((c1.x > kb) || (c1.x == kb && c1.y > pay)) ? 1 : 0;
            rank += ((c2.x > kb) || (c2.x == kb && c2.y > pay)) ? 1 : 0;
            rank += ((c3.x > kb) || (c3.x == kb && c3.y > pay)) ? 1 : 0;
        }
        #pragma unroll 1
        for (; e < total; ++e) {
            int2 c = s_cand[e];
            rank += ((c.x > kb) || (c.x == kb && c.y > pay)) ? 1 : 0;
        }
        if (lane < total && rank < 10) s_win[rank] = make_int2(kb, pay);
        asm volatile("s_waitcnt lgkmcnt(0)" ::: "memory");
        #pragma unroll
        for (int r = 0; r < 10; ++r) {
            int2 wr = s_win[r];
            wi[r] = 1023 - (wr.y >> 1);
            wv[r] = __int_as_float(wr.x | ((wr.y & 1) << 31));
        }
        tbits = __float_as_int(wv[9]) & 0x7fffffff;
    } else {
        top10_full(k, sgn, lane, wi, wv);
        tbits = __float_as_int(wv[9]) & 0x7fffffff;
    }
}

// c = b + sum_k wv[k] * S[wi[k], :]  (S numerically symmetric -> row access;
// wi wave-uniform -> scalar base addressing)
__device__ __forceinline__ void gather_ista(const float bz[16], float cz[16],
                                            const float* __restrict__ S,
                                            const int wi[10], const float wv[10], int lane) {
    #pragma unroll
    for (int s = 0; s < 16; ++s) cz[s] = bz[s];
    #pragma unroll
    for (int kk = 0; kk < 10; ++kk) {
        int row = __builtin_amdgcn_readfirstlane(wi[kk]);
        const float4* sp = (const float4*)(S + (size_t)row * DIM + (lane << 4));
        const float wvs = wv[kk];
        #pragma unroll
        for (int q = 0; q < 4; ++q) {
            float4 v = sp[q];
            cz[q*4+0] += wvs * v.x;
            cz[q*4+1] += wvs * v.y;
            cz[q*4+2] += wvs * v.z;
            cz[q*4+3] += wvs * v.w;
        }
    }
}

// ============================================================================
// Warm-up: z=thr(b); c=b+z@S^T; z=thr(c) -> sparse (idx,val). 4 waves/block.
// ============================================================================
__global__ __launch_bounds__(256)
void warmup_rows(const float* __restrict__ b, const float* __restrict__ S,
                 int* __restrict__ sidx, float* __restrict__ sval) {
    __shared__ int2 s_cand[4][64];
    __shared__ int2 s_win[4][16];
    const int tid = threadIdx.x, lane = tid & 63, wid = tid >> 6;
    const int r = blockIdx.x * 4 + wid;
    const float* bp = b + (size_t)r * DIM + (lane << 4);
    float bz[16];
    #pragma unroll
    for (int q = 0; q < 4; ++q) {
        float4 v = ((const float4*)bp)[q];
        bz[q*4+0] = v.x; bz[q*4+1] = v.y; bz[q*4+2] = v.z; bz[q*4+3] = v.w;
    }
    int wi[10]; float wv[10]; int tbits = 0;
    select10<false>(bz, lane, s_cand[wid], s_win[wid], tbits, wi, wv);
    float cz[16];
    gather_ista(bz, cz, S, wi, wv, lane);
    select10<true>(cz, lane, s_cand[wid], s_win[wid], tbits, wi, wv);
    if (lane == 0) {
        #pragma unroll
        for (int kk = 0; kk < 10; ++kk) { sidx[r*10+kk] = wi[kk]; sval[r*10+kk] = wv[kk]; }
    }
}

// ============================================================================
// Main loop: z=thr(c1); 9 x { c=b+z@S^T; z=thr(c) } with exact fixed-point
// early exit. Writes dense z + sparse (idx,val). 4 waves/block.
// ============================================================================
__global__ __launch_bounds__(256)
void loop_rows(const float* __restrict__ c1, const float* __restrict__ b,
               const float* __restrict__ S, float* __restrict__ zout,
               int* __restrict__ sidx, float* __restrict__ sval) {
    __shared__ int2 s_cand[4][64];
    __shared__ int2 s_win[4][16];
    const int tid = threadIdx.x, lane = tid & 63, wid = tid >> 6;
    const int r = blockIdx.x * 4 + wid;
    const float* bp = b  + (size_t)r * DIM + (lane << 4);
    const float* cp = c1 + (size_t)r * DIM + (lane << 4);
    float bz[16], cz[16];
    #pragma unroll
    for (int q = 0; q < 4; ++q) {
        float4 v = ((const float4*)bp)[q];
        bz[q*4+0] = v.x; bz[q*4+1] = v.y; bz[q*4+2] = v.z; bz[q*4+3] = v.w;
        float4 u = ((const float4*)cp)[q];
        cz[q*4+0] = u.x; cz[q*4+1] = u.y; cz[q*4+2] = u.z; cz[q*4+3] = u.w;
    }
    int wi[10]; float wv[10]; int tbits = 0;
    select10<false>(cz, lane, s_cand[wid], s_win[wid], tbits, wi, wv);
    int pwi[10], pwb[10];
    #pragma unroll 1
    for (int it = 0; it < 9; ++it) {
        #pragma unroll
        for (int kk = 0; kk < 10; ++kk) { pwi[kk] = wi[kk]; pwb[kk] = __float_as_int(wv[kk]); }
        gather_ista(bz, cz, S, wi, wv, lane);
        select10<true>(cz, lane, s_cand[wid], s_win[wid], tbits, wi, wv);
        bool same = true;
        #pragma unroll
        for (int kk = 0; kk < 10; ++kk)
            same = same && (wi[kk] == pwi[kk]) && (__float_as_int(wv[kk]) == pwb[kk]);
        if (same) break;   // exact fixed point: remaining iterations identical
    }
    #pragma unroll
    for (int q = 0; q < 4; ++q) {
        float e[4];
        #pragma unroll
        for (int t = 0; t < 4; ++t) {
            int j = (lane << 4) | (q*4 + t);
            float v = 0.0f;
            #pragma unroll
            for (int kk = 0; kk < 10; ++kk) v = (wi[kk] == j) ? wv[kk] : v;
            e[t] = v;
        }
        float4 o; o.x = e[0]; o.y = e[1]; o.z = e[2]; o.w = e[3];
        ((float4*)(zout + (size_t)r * DIM + (lane << 4)))[q] = o;
    }
    if (lane == 0) {
        #pragma unroll
        for (int kk = 0; kk < 10; ++kk) { sidx[r*10+kk] = wi[kk]; sval[r*10+kk] = wv[kk]; }
    }
}

// ============================================================================
// GEMM: C[m,n] = (sum_k A[m,k]*B[n,k]) [/L] [+ add[m,n]]  (C = A @ B^T)
// 128x128 tile, BK=16, 256 threads, 8x8 per thread, register prefetch.
// ============================================================================
template<bool DIV_L, bool HAS_ADD>
__global__ __launch_bounds__(256)
void gemm256(const float* __restrict__ A, const float* __restrict__ B,
             const float* __restrict__ addM, float* __restrict__ C,
             const float* __restrict__ Lptr, int M, int N, int K) {
    __shared__ float As[16][136];   // 136*4B = 16B multiple: aligned b128 rows
    __shared__ float Bs[16][136];
    const int tid = threadIdx.x;
    const int m0 = blockIdx.y * 128, n0 = blockIdx.x * 128;
    const int ty = tid >> 4, tx = tid & 15;   // 16x16 thread grid, 8x8 each
    const int srow = tid >> 1;                // 0..127
    const int sk   = (tid & 1) * 8;           // 0 or 8
    float acc[8][8] = {};
    const float* Ab = A + (size_t)(m0 + srow) * K + sk;
    const float* Bb = B + (size_t)(n0 + srow) * K + sk;
    float4 av0 = *(const float4*)(Ab);
    float4 av1 = *(const float4*)(Ab + 4);
    float4 bv0 = *(const float4*)(Bb);
    float4 bv1 = *(const float4*)(Bb + 4);
    for (int k0 = 0; k0 < K; k0 += 16) {
        __syncthreads();
        As[sk+0][srow] = av0.x; As[sk+1][srow] = av0.y; As[sk+2][srow] = av0.z; As[sk+3][srow] = av0.w;
        As[sk+4][srow] = av1.x; As[sk+5][srow] = av1.y; As[sk+6][srow] = av1.z; As[sk+7][srow] = av1.w;
        Bs[sk+0][srow] = bv0.x; Bs[sk+1][srow] = bv0.y; Bs[sk+2][srow] = bv0.z; Bs[sk+3][srow] = bv0.w;
        Bs[sk+4][srow] = bv1.x; Bs[sk+5][srow] = bv1.y; Bs[sk+6][srow] = bv1.z; Bs[sk+7][srow] = bv1.w;
        __syncthreads();
        if (k0 + 16 < K) {   // prefetch next tile; latency hides under FMAs
            av0 = *(const float4*)(Ab + k0 + 16);
            av1 = *(const float4*)(Ab + k0 + 20);
            bv0 = *(const float4*)(Bb + k0 + 16);
            bv1 = *(const float4*)(Bb + k0 + 20);
        }
        #pragma unroll
        for (int k = 0; k < 16; ++k) {
            float4 a40 = *(const float4*)&As[k][ty*8];
            float4 a41 = *(const float4*)&As[k][ty*8+4];
            float4 b40 = *(const float4*)&Bs[k][tx*8];
            float4 b41 = *(const float4*)&Bs[k][tx*8+4];
            float am[8] = {a40.x,a40.y,a40.z,a40.w,a41.x,a41.y,a41.z,a41.w};
            float bn[8] = {b40.x,b40.y,b40.z,b40.w,b41.x,b41.y,b41.z,b41.w};
            #pragma unroll
            for (int i = 0; i < 8; ++i)
                #pragma unroll
                for (int j = 0; j < 8; ++j)
                    acc[i][j] += am[i] * bn[j];
        }
    }
    const float invL = DIV_L ? (1.0f / *Lptr) : 1.0f;
    #pragma unroll
    for (int i = 0; i < 8; ++i) {
        size_t row = (size_t)(m0 + ty*8 + i);
        float* Cp = C + row * N + n0 + tx*8;
        const float* Ap = HAS_ADD ? (addM + row * N + n0 + tx*8) : nullptr;
        #pragma unroll
        for (int j = 0; j < 8; ++j) {
            float r = acc[i][j];
            if (DIV_L) r *= invL;
            if (HAS_ADD) r += Ap[j];
            Cp[j] = r;
        }
    }
}

// ============================================================================
// Spectral density from sparse z (deterministic two-stage)
// ============================================================================
__global__ void sparse_density_stage1(const int* __restrict__ sidx,
                                      const float* __restrict__ sval,
                                      float* __restrict__ partial) {
    const int w = threadIdx.x;            // 512
    const int blk = blockIdx.x;           // 64 blocks x 64 rows
    const int base = blk * 64 * 10;
    float acc = 0.0f;
    for (int e = 0; e < 640; ++e) {
        int d = sidx[base + e];
        float v = sval[base + e];
        if ((d & 511) == w) acc += v * v;
    }
    partial[blk * 512 + w] = acc;
}

// ============================================================================
// prev_windows spectral density
// ============================================================================
__global__ void prev_density_stage1(const float* __restrict__ pw, float* __restrict__ partial) {
    const int p = blockIdx.x, chunk = blockIdx.y;   // (8, 64)
    const int w = threadIdx.x;                      // 512
    const float* base = pw + ((size_t)p * BATCH + (size_t)chunk * 64) * DIM;
    float acc = 0.0f;
    for (int i = 0; i < 64; ++i) {
        float a = base[(size_t)i * DIM + w];
        float c = base[(size_t)i * DIM + 512 + w];
        acc += a * a + c * c;
    }
    partial[((size_t)(p * 64 + chunk)) * 512 + w] = acc;
}

__global__ void prev_density_stage2(const float* __restrict__ partial, float* __restrict__ mD_prev) {
    const int p = blockIdx.x; const int w = threadIdx.x;
    float acc = 0.0f;
    for (int i = 0; i < 64; ++i) acc += partial[((size_t)(p * 64 + i)) * 512 + w];
    mD_prev[p * 512 + w] = acc;
}

// ============================================================================
// Fused: mD1 = col-sum of partials; normalize; attention logits; softmax.
// One block, 512 threads (8 waves; wave p handles prev-window p).
// ============================================================================
__device__ __forceinline__ float wave_fmax(float v) {
    #pragma unroll
    for (int m = 1; m < 64; m <<= 1) v = fmaxf(v, __shfl_xor(v, m));
    return v;
}
__device__ __forceinline__ float wave_fmin(float v) {
    #pragma unroll
    for (int m = 1; m < 64; m <<= 1) v = fminf(v, __shfl_xor(v, m));
    return v;
}
__device__ __forceinline__ float wave_fsum(float v) {
    #pragma unroll
    for (int m = 1; m < 64; m <<= 1) v += __shfl_xor(v, m);
    return v;
}

__global__ void density2_attention(const float* __restrict__ partial,
                                   const float* __restrict__ mD_prev,
                                   float* __restrict__ att) {
    __shared__ float md1[512];
    __shared__ float att_l[PPREV];
    const int tid = threadIdx.x, lane = tid & 63, w = tid >> 6;
    float v = 0.0f;
    for (int i = 0; i < 64; ++i) v += partial[i * 512 + tid];
    md1[tid] = v;
    __syncthreads();
    float t8[8], u8[8];
    {
        const float4* m4 = (const float4*)(&md1[lane * 8]);
        float4 a = m4[0], bq = m4[1];
        t8[0]=a.x; t8[1]=a.y; t8[2]=a.z; t8[3]=a.w; t8[4]=bq.x; t8[5]=bq.y; t8[6]=bq.z; t8[7]=bq.w;
        const float4* p4 = (const float4*)(mD_prev + w * 512 + lane * 8);
        float4 c = p4[0], d = p4[1];
        u8[0]=c.x; u8[1]=c.y; u8[2]=c.z; u8[3]=c.w; u8[4]=d.x; u8[5]=d.y; u8[6]=d.z; u8[7]=d.w;
    }
    float mx = t8[0], mn = t8[0], pmx = u8[0], pmn = u8[0];
    #pragma unroll
    for (int i = 1; i < 8; ++i) {
        mx = fmaxf(mx, t8[i]); mn = fminf(mn, t8[i]);
        pmx = fmaxf(pmx, u8[i]); pmn = fminf(pmn, u8[i]);
    }
    mx = wave_fmax(mx); mn = wave_fmin(mn);
    pmx = wave_fmax(pmx); pmn = wave_fmin(pmn);
    const float inv  = 1.0f / (mx - mn + 1e-8f);
    const float pinv = 1.0f / (pmx - pmn + 1e-8f);
    float dot = 0.0f;
    #pragma unroll
    for (int i = 0; i < 8; ++i) dot += ((u8[i] - pmn) * pinv) * ((t8[i] - mn) * inv);
    dot = wave_fsum(dot);
    if (lane == 0) att_l[w] = dot / 22.627417f;   // np.float32(sqrt(512))
    __syncthreads();
    if (tid == 0) {
        float m = att_l[0];
        #pragma unroll
        for (int p = 1; p < PPREV; ++p) m = fmaxf(m, att_l[p]);
        float e[PPREV], s = 0.0f;
        #pragma unroll
        for (int p = 0; p < PPREV; ++p) { e[p] = expf(att_l[p] - m); s += e[p]; }
        #pragma unroll
        for (int p = 0; p < PPREV; ++p) att[p] = e[p] / s;
    }
}

// ============================================================================
// z_att = lambda2 * sum_p clip(pw[p], +-150) * att[p]
// ============================================================================
__global__ __launch_bounds__(256)
void weighted_sum(const float* __restrict__ pw, const float* __restrict__ att,
                  const float* __restrict__ lam, float* __restrict__ zatt) {
    const size_t i = ((size_t)blockIdx.x * 256 + threadIdx.x) * 4;
    const float l2 = *lam;
    float a[PPREV];
    #pragma unroll
    for (int p = 0; p < PPREV; ++p) a[p] = att[p];
    float4 acc = make_float4(0.f, 0.f, 0.f, 0.f);
    #pragma unroll
    for (int p = 0; p < PPREV; ++p) {
        float4 v = *(const float4*)(pw + (size_t)p * BATCH * DIM + i);
        v.x = fminf(fmaxf(v.x, -150.f), 150.f);
        v.y = fminf(fmaxf(v.y, -150.f), 150.f);
        v.z = fminf(fmaxf(v.z, -150.f), 150.f);
        v.w = fminf(fmaxf(v.w, -150.f), 150.f);
        acc.x += v.x * a[p]; acc.y += v.y * a[p]; acc.z += v.z * a[p]; acc.w += v.w * a[p];
    }
    acc.x *= l2; acc.y *= l2; acc.z *= l2; acc.w *= l2;
    *(float4*)(zatt + i) = acc;
}

// ============================================================================
// Final: mD2 = col-sum of partials, min-max normalize into out[0:512]
// ============================================================================
__global__ void finalize_fused(const float* __restrict__ partial, float* __restrict__ out) {
    __shared__ float red[512];
    const int tid = threadIdx.x;
    float v = 0.0f;
    for (int i = 0; i < 64; ++i) v += partial[i * 512 + tid];
    red[tid] = v; __syncthreads();
    for (int off = 256; off > 0; off >>= 1) { if (tid < off) red[tid] = fmaxf(red[tid], red[tid+off]); __syncthreads(); }
    float mx = red[0]; __syncthreads();
    red[tid] = v; __syncthreads();
    for (int off = 256; off > 0; off >>= 1) { if (tid < off) red[tid] = fminf(red[tid], red[tid+off]); __syncthreads(); }
    float mn = red[0];
    out[tid] = (v - mn) / (mx - mn + 1e-8f);
}

// ============================================================================
extern "C" void kernel_launch(void* const* d_in, const int* in_sizes, int n_in,
                              void* d_out, int out_size, void* d_ws, size_t ws_size,
                              hipStream_t stream) {
    const float* x   = (const float*)d_in[0];   // [4096,1024]
    const float* pw  = (const float*)d_in[1];   // [8,4096,1024]
    const float* Wd  = (const float*)d_in[2];   // [1,1024,1024]
    const float* S   = (const float*)d_in[3];   // [1,1024,1024] (numerically symmetric)
    const float* lam = (const float*)d_in[4];   // scalar
    const float* L   = (const float*)d_in[5];   // scalar
    float* out = (float*)d_out;                 // [512] ++ [4096*1024]

    float* b       = (float*)d_ws;                      // 4,194,304
    float* zatt    = b + (size_t)BATCH * DIM;           // 4,194,304
    float* pp_prev = zatt + (size_t)BATCH * DIM;        // 262,144
    float* pp_dens = pp_prev + 262144;                  // 32,768
    float* mD_prev = pp_dens + 32768;                   // 4096
    float* attw    = mD_prev + 4096;                    // 8
    float* sval1   = attw + 8;                          // 40,960
    float* sval2   = sval1 + 40960;                     // 40,960
    int*   sidx1   = (int*)(sval2 + 40960);             // 40,960 ints
    int*   sidx2   = sidx1 + 40960;                     // 40,960 ints

    float* c1   = out + 512;   // stage c1 in output z region (rewritten by loop_rows)
    float* zout = out + 512;

    const dim3 gg(DIM / 128, BATCH / 128);   // (8, 32)

    gemm256<true,  false><<<gg, 256, 0, stream>>>(x, Wd, nullptr, b, L, BATCH, DIM, DIM);
    warmup_rows<<<BATCH / 4, 256, 0, stream>>>(b, S, sidx1, sval1);
    sparse_density_stage1<<<64, 512, 0, stream>>>(sidx1, sval1, pp_dens);
    prev_density_stage1<<<dim3(PPREV, 64), 512, 0, stream>>>(pw, pp_prev);
    prev_density_stage2<<<PPREV, 512, 0, stream>>>(pp_prev, mD_prev);
    density2_attention<<<1, 512, 0, stream>>>(pp_dens, mD_prev, attw);
    weighted_sum<<<(BATCH * DIM) / 1024, 256, 0, stream>>>(pw, attw, lam, zatt);
    gemm256<false, true ><<<gg, 256, 0, stream>>>(zatt, S, b, c1, nullptr, BATCH, DIM, DIM);
    loop_rows<<<BATCH / 4, 256, 0, stream>>>(c1, b, S, zout, sidx2, sval2);
    sparse_density_stage1<<<64, 512, 0, stream>>>(sidx2, sval2, pp_dens);
    finalize_fused<<<1, 512, 0, stream>>>(pp_dens, out);
}

// Round 5
// 527.272 us; speedup vs baseline: 1.1580x; 1.1580x over previous
//
#include <hip/hip_runtime.h>
#include <stdint.h>

#define BATCH 4096
#define DIM   1024
#define PPREV 8
#define CAP   128

// popcount of mask over lanes strictly below the current lane
__device__ __forceinline__ int lt_count(unsigned long long m) {
    return __builtin_amdgcn_mbcnt_hi((unsigned)(m >> 32),
           __builtin_amdgcn_mbcnt_lo((unsigned)m, 0));
}
__device__ __forceinline__ bool kp_gt(int ak, int ap, int bk, int bp) {
    return (ak > bk) || (ak == bk && ap > bp);
}

// ============================================================================
// Block-cooperative top-10 by |value|, exact jax.lax.top_k tie-break (lowest
// flat index wins among ties). 256 threads/row; thread owns j = tid*4+t.
// Key = |f32 bits| (int compare == magnitude compare);
// payload = ((1023-j)<<1)|sign  ->  (key,pay) lex-desc == (value desc, idx asc).
// ============================================================================
template<bool SEEDED>
__device__ __forceinline__ void select10_block(
    const float cz[4], int tid, int lane, int wid,
    int2* s_cand, int2* s_win, int* s_cnt, int2* s_red, int* s_bnd,
    int& tbits, int wi[10], float wv[10])
{
    int k[4], pay[4];
    #pragma unroll
    for (int t = 0; t < 4; ++t) {
        int bb = __float_as_int(cz[t]);
        k[t]   = bb & 0x7fffffff;
        pay[t] = ((1023 - (tid * 4 + t)) << 1) | (int)((unsigned)bb >> 31);
    }

    if (!SEEDED) {
        // valid lower bound for the 10th-largest: per wave, the 10th-largest
        // of its 64 per-lane maxima (10 distinct elements >= it); block bound
        // = max over waves (the achieving wave provides the 10 witnesses).
        int lm = max(max(k[0], k[1]), max(k[2], k[3]));
        #pragma unroll
        for (int k2 = 2; k2 <= 64; k2 <<= 1) {
            #pragma unroll
            for (int j = k2 >> 1; j > 0; j >>= 1) {
                int p = __shfl_xor(lm, j);
                bool keep_max = (((lane & k2) == 0) == ((lane & j) == 0));
                if ((p > lm) == keep_max) lm = p;
            }
        }
        int wb = __builtin_amdgcn_readlane(lm, 9);
        if (lane == 0) s_bnd[wid] = wb;
        __syncthreads();
        tbits = max(max(s_bnd[0], s_bnd[1]), max(s_bnd[2], s_bnd[3]));
    }

    int tb = tbits;
    #pragma unroll 1
    for (;;) {
        unsigned long long b0 = __ballot(k[0] >= tb);
        unsigned long long b1 = __ballot(k[1] >= tb);
        unsigned long long b2 = __ballot(k[2] >= tb);
        unsigned long long b3 = __ballot(k[3] >= tb);
        int wcnt = __popcll(b0) + __popcll(b1) + __popcll(b2) + __popcll(b3);
        if (lane == 0) s_cnt[wid] = wcnt;
        __syncthreads();
        const int c0 = s_cnt[0], c1 = s_cnt[1], c2 = s_cnt[2], c3 = s_cnt[3];
        const int total = c0 + c1 + c2 + c3;
        __syncthreads();                      // counts consumed; safe to rewrite

        if (total >= 10) {
            if (total <= CAP) {
                int off = (wid > 0 ? c0 : 0) + (wid > 1 ? c1 : 0) + (wid > 2 ? c2 : 0);
                int o0 = off + lt_count(b0);  off += __popcll(b0);
                int o1 = off + lt_count(b1);  off += __popcll(b1);
                int o2 = off + lt_count(b2);  off += __popcll(b2);
                int o3 = off + lt_count(b3);
                if (k[0] >= tb) s_cand[o0] = make_int2(k[0], pay[0]);
                if (k[1] >= tb) s_cand[o1] = make_int2(k[1], pay[1]);
                if (k[2] >= tb) s_cand[o2] = make_int2(k[2], pay[2]);
                if (k[3] >= tb) s_cand[o3] = make_int2(k[3], pay[3]);
                __syncthreads();
                if (tid < total) {
                    int2 mine = s_cand[tid];
                    int rank = 0, e = 0;
                    #pragma unroll 1
                    for (; e + 4 <= total; e += 4) {
                        int2 q0 = s_cand[e], q1 = s_cand[e+1], q2 = s_cand[e+2], q3 = s_cand[e+3];
                        rank += kp_gt(q0.x, q0.y, mine.x, mine.y) ? 1 : 0;
                        rank += kp_gt(q1.x, q1.y, mine.x, mine.y) ? 1 : 0;
                        rank += kp_gt(q2.x, q2.y, mine.x, mine.y) ? 1 : 0;
                        rank += kp_gt(q3.x, q3.y, mine.x, mine.y) ? 1 : 0;
                    }
                    #pragma unroll 1
                    for (; e < total; ++e) {
                        int2 q = s_cand[e];
                        rank += kp_gt(q.x, q.y, mine.x, mine.y) ? 1 : 0;
                    }
                    if (rank < 10) s_win[rank] = mine;   // strict order -> unique ranks
                }
                __syncthreads();
            } else {
                // rare fallback: 10 rounds of exact block argmax
                #pragma unroll 1
                for (int r = 0; r < 10; ++r) {
                    int bk = k[0], bp = pay[0];
                    #pragma unroll
                    for (int t = 1; t < 4; ++t)
                        if (kp_gt(k[t], pay[t], bk, bp)) { bk = k[t]; bp = pay[t]; }
                    #pragma unroll
                    for (int m = 1; m < 64; m <<= 1) {
                        int ok = __shfl_xor(bk, m), op = __shfl_xor(bp, m);
                        if (kp_gt(ok, op, bk, bp)) { bk = ok; bp = op; }
                    }
                    if (lane == 0) s_red[wid] = make_int2(bk, bp);
                    __syncthreads();
                    if (tid == 0) {
                        int2 best = s_red[0];
                        #pragma unroll
                        for (int w2 = 1; w2 < 4; ++w2) {
                            int2 cc = s_red[w2];
                            if (kp_gt(cc.x, cc.y, best.x, best.y)) best = cc;
                        }
                        s_win[r] = best;
                    }
                    __syncthreads();
                    int2 wr = s_win[r];
                    #pragma unroll
                    for (int t = 0; t < 4; ++t)
                        if (k[t] == wr.x && pay[t] == wr.y) k[t] = -1;   // pay unique
                }
            }
            break;
        }
        tb = (tb > 0x00800000) ? (tb - 0x00800000) : 0;   // halve threshold
    }

    #pragma unroll
    for (int r = 0; r < 10; ++r) {
        int2 wr = s_win[r];
        wi[r] = 1023 - (wr.y >> 1);
        wv[r] = __int_as_float(wr.x | ((wr.y & 1) << 31));
    }
    tbits = __float_as_int(wv[9]) & 0x7fffffff;
}

// c = b + sum_k wv[k] * S[wi[k], :]  (S numerically symmetric -> row access;
// wi block-uniform -> scalar base addressing; coalesced float4 per thread)
__device__ __forceinline__ void gather_block(const float bz[4], float cz[4],
                                             const float* __restrict__ S,
                                             const int wi[10], const float wv[10], int tid)
{
    #pragma unroll
    for (int t = 0; t < 4; ++t) cz[t] = bz[t];
    #pragma unroll
    for (int kk = 0; kk < 10; ++kk) {
        int row = __builtin_amdgcn_readfirstlane(wi[kk]);
        const float wvs = wv[kk];
        float4 v = *(const float4*)(S + (size_t)row * DIM + tid * 4);
        cz[0] += wvs * v.x;
        cz[1] += wvs * v.y;
        cz[2] += wvs * v.z;
        cz[3] += wvs * v.w;
    }
}

// ============================================================================
// Warm-up: z=thr(b); c=b+z@S^T; z=thr(c) -> sparse (idx,val). 1 block/row.
// ============================================================================
__global__ __launch_bounds__(256)
void warmup_rows(const float* __restrict__ b, const float* __restrict__ S,
                 int* __restrict__ sidx, float* __restrict__ sval)
{
    __shared__ int2 s_cand[CAP];
    __shared__ int2 s_win[10];
    __shared__ int2 s_red[4];
    __shared__ int  s_cnt[4];
    __shared__ int  s_bnd[4];
    const int tid = threadIdx.x, lane = tid & 63, wid = tid >> 6;
    const int r = blockIdx.x;
    float4 bv = *(const float4*)(b + (size_t)r * DIM + tid * 4);
    float bz[4] = {bv.x, bv.y, bv.z, bv.w};
    int wi[10]; float wv[10]; int tbits = 0;
    select10_block<false>(bz, tid, lane, wid, s_cand, s_win, s_cnt, s_red, s_bnd, tbits, wi, wv);
    float cz[4];
    gather_block(bz, cz, S, wi, wv, tid);
    select10_block<true>(cz, tid, lane, wid, s_cand, s_win, s_cnt, s_red, s_bnd, tbits, wi, wv);
    if (tid < 10) {
        int2 wr = s_win[tid];
        sidx[r * 10 + tid] = 1023 - (wr.y >> 1);
        sval[r * 10 + tid] = __int_as_float(wr.x | ((wr.y & 1) << 31));
    }
}

// ============================================================================
// Main loop: z=thr(c1); 9 x { c=b+z@S^T; z=thr(c) } with exact fixed-point
// early exit (block-uniform). Writes dense z + sparse. 1 block/row.
// ============================================================================
__global__ __launch_bounds__(256)
void loop_rows(const float* __restrict__ c1, const float* __restrict__ b,
               const float* __restrict__ S, float* __restrict__ zout,
               int* __restrict__ sidx, float* __restrict__ sval)
{
    __shared__ int2 s_cand[CAP];
    __shared__ int2 s_win[10];
    __shared__ int2 s_red[4];
    __shared__ int  s_cnt[4];
    __shared__ int  s_bnd[4];
    const int tid = threadIdx.x, lane = tid & 63, wid = tid >> 6;
    const int r = blockIdx.x;
    float4 bv = *(const float4*)(b  + (size_t)r * DIM + tid * 4);
    float4 cv = *(const float4*)(c1 + (size_t)r * DIM + tid * 4);
    float bz[4] = {bv.x, bv.y, bv.z, bv.w};
    float cz[4] = {cv.x, cv.y, cv.z, cv.w};
    int wi[10]; float wv[10]; int tbits = 0;
    select10_block<false>(cz, tid, lane, wid, s_cand, s_win, s_cnt, s_red, s_bnd, tbits, wi, wv);
    int pwi[10], pwb[10];
    #pragma unroll 1
    for (int it = 0; it < 9; ++it) {
        #pragma unroll
        for (int kk = 0; kk < 10; ++kk) { pwi[kk] = wi[kk]; pwb[kk] = __float_as_int(wv[kk]); }
        gather_block(bz, cz, S, wi, wv, tid);
        select10_block<true>(cz, tid, lane, wid, s_cand, s_win, s_cnt, s_red, s_bnd, tbits, wi, wv);
        bool same = true;
        #pragma unroll
        for (int kk = 0; kk < 10; ++kk)
            same = same && (wi[kk] == pwi[kk]) && (__float_as_int(wv[kk]) == pwb[kk]);
        if (same) break;   // exact fixed point: remaining iterations identical
    }
    float e[4];
    #pragma unroll
    for (int t = 0; t < 4; ++t) {
        const int j = tid * 4 + t;
        float v = 0.0f;
        #pragma unroll
        for (int kk = 0; kk < 10; ++kk) v = (wi[kk] == j) ? wv[kk] : v;
        e[t] = v;
    }
    float4 o; o.x = e[0]; o.y = e[1]; o.z = e[2]; o.w = e[3];
    *(float4*)(zout + (size_t)r * DIM + tid * 4) = o;
    if (tid < 10) {
        int2 wr = s_win[tid];
        sidx[r * 10 + tid] = 1023 - (wr.y >> 1);
        sval[r * 10 + tid] = __int_as_float(wr.x | ((wr.y & 1) << 31));
    }
}

// ============================================================================
// GEMM: C[m,n] = (sum_k A[m,k]*B[n,k]) [/L] [+ add[m,n]]  (C = A @ B^T)
// 128x64 tile, BK=16, 256 threads, 8x4 per thread, register prefetch.
// Grid = 512 blocks -> 2 blocks/CU (staging of one overlaps compute of other).
// ============================================================================
template<bool DIV_L, bool HAS_ADD>
__global__ __launch_bounds__(256)
void gemm_f32(const float* __restrict__ A, const float* __restrict__ B,
              const float* __restrict__ addM, float* __restrict__ C,
              const float* __restrict__ Lptr, int M, int N, int K)
{
    __shared__ float As[16][132];   // 132*4B = 16B multiple: aligned b128 rows
    __shared__ float Bs[16][68];
    const int tid = threadIdx.x;
    const int m0 = blockIdx.y * 128, n0 = blockIdx.x * 64;
    const int ty = tid >> 4, tx = tid & 15;   // 16x16 threads, 8x4 each
    const int sarow = tid >> 1;               // 0..127
    const int sak   = (tid & 1) * 8;          // 0 or 8
    const int sbrow = tid >> 2;               // 0..63
    const int sbk   = (tid & 3) * 4;          // 0,4,8,12
    float acc[8][4] = {};
    const float* Ab = A + (size_t)(m0 + sarow) * K + sak;
    const float* Bb = B + (size_t)(n0 + sbrow) * K + sbk;
    float4 av0 = *(const float4*)(Ab);
    float4 av1 = *(const float4*)(Ab + 4);
    float4 bv0 = *(const float4*)(Bb);
    for (int k0 = 0; k0 < K; k0 += 16) {
        __syncthreads();
        As[sak+0][sarow] = av0.x; As[sak+1][sarow] = av0.y; As[sak+2][sarow] = av0.z; As[sak+3][sarow] = av0.w;
        As[sak+4][sarow] = av1.x; As[sak+5][sarow] = av1.y; As[sak+6][sarow] = av1.z; As[sak+7][sarow] = av1.w;
        Bs[sbk+0][sbrow] = bv0.x; Bs[sbk+1][sbrow] = bv0.y; Bs[sbk+2][sbrow] = bv0.z; Bs[sbk+3][sbrow] = bv0.w;
        __syncthreads();
        if (k0 + 16 < K) {   // prefetch next K-tile; hides under FMAs
            av0 = *(const float4*)(Ab + k0 + 16);
            av1 = *(const float4*)(Ab + k0 + 20);
            bv0 = *(const float4*)(Bb + k0 + 16);
        }
        #pragma unroll
        for (int k = 0; k < 16; ++k) {
            float4 a40 = *(const float4*)&As[k][ty*8];
            float4 a41 = *(const float4*)&As[k][ty*8+4];
            float4 b40 = *(const float4*)&Bs[k][tx*4];
            float am[8] = {a40.x,a40.y,a40.z,a40.w,a41.x,a41.y,a41.z,a41.w};
            float bn[4] = {b40.x,b40.y,b40.z,b40.w};
            #pragma unroll
            for (int i = 0; i < 8; ++i)
                #pragma unroll
                for (int j = 0; j < 4; ++j)
                    acc[i][j] += am[i] * bn[j];
        }
    }
    const float invL = DIV_L ? (1.0f / *Lptr) : 1.0f;
    #pragma unroll
    for (int i = 0; i < 8; ++i) {
        size_t row = (size_t)(m0 + ty*8 + i);
        float4 rv; 
        rv.x = acc[i][0]; rv.y = acc[i][1]; rv.z = acc[i][2]; rv.w = acc[i][3];
        if (DIV_L) { rv.x *= invL; rv.y *= invL; rv.z *= invL; rv.w *= invL; }
        if (HAS_ADD) {
            float4 ad = *(const float4*)(addM + row * N + n0 + tx*4);
            rv.x += ad.x; rv.y += ad.y; rv.z += ad.z; rv.w += ad.w;
        }
        *(float4*)(C + row * N + n0 + tx*4) = rv;
    }
}

// ============================================================================
// Spectral density from sparse z (deterministic two-stage)
// ============================================================================
__global__ void sparse_density_stage1(const int* __restrict__ sidx,
                                      const float* __restrict__ sval,
                                      float* __restrict__ partial)
{
    const int w = threadIdx.x;            // 512
    const int blk = blockIdx.x;           // 64 blocks x 64 rows
    const int base = blk * 64 * 10;
    float acc = 0.0f;
    for (int e = 0; e < 640; ++e) {
        int d = sidx[base + e];
        float v = sval[base + e];
        if ((d & 511) == w) acc += v * v;
    }
    partial[blk * 512 + w] = acc;
}

// ============================================================================
// prev_windows spectral density
// ============================================================================
__global__ void prev_density_stage1(const float* __restrict__ pw, float* __restrict__ partial)
{
    const int p = blockIdx.x, chunk = blockIdx.y;   // (8, 64)
    const int w = threadIdx.x;                      // 512
    const float* base = pw + ((size_t)p * BATCH + (size_t)chunk * 64) * DIM;
    float acc = 0.0f;
    for (int i = 0; i < 64; ++i) {
        float a = base[(size_t)i * DIM + w];
        float c = base[(size_t)i * DIM + 512 + w];
        acc += a * a + c * c;
    }
    partial[((size_t)(p * 64 + chunk)) * 512 + w] = acc;
}

__global__ void prev_density_stage2(const float* __restrict__ partial, float* __restrict__ mD_prev)
{
    const int p = blockIdx.x; const int w = threadIdx.x;
    float acc = 0.0f;
    for (int i = 0; i < 64; ++i) acc += partial[((size_t)(p * 64 + i)) * 512 + w];
    mD_prev[p * 512 + w] = acc;
}

// ============================================================================
// Fused: mD1 = col-sum of partials; normalize; attention logits; softmax.
// ============================================================================
__device__ __forceinline__ float wave_fmax(float v) {
    #pragma unroll
    for (int m = 1; m < 64; m <<= 1) v = fmaxf(v, __shfl_xor(v, m));
    return v;
}
__device__ __forceinline__ float wave_fmin(float v) {
    #pragma unroll
    for (int m = 1; m < 64; m <<= 1) v = fminf(v, __shfl_xor(v, m));
    return v;
}
__device__ __forceinline__ float wave_fsum(float v) {
    #pragma unroll
    for (int m = 1; m < 64; m <<= 1) v += __shfl_xor(v, m);
    return v;
}

__global__ void density2_attention(const float* __restrict__ partial,
                                   const float* __restrict__ mD_prev,
                                   float* __restrict__ att)
{
    __shared__ float md1[512];
    __shared__ float att_l[PPREV];
    const int tid = threadIdx.x, lane = tid & 63, w = tid >> 6;
    float v = 0.0f;
    for (int i = 0; i < 64; ++i) v += partial[i * 512 + tid];
    md1[tid] = v;
    __syncthreads();
    float t8[8], u8[8];
    {
        const float4* m4 = (const float4*)(&md1[lane * 8]);
        float4 a = m4[0], bq = m4[1];
        t8[0]=a.x; t8[1]=a.y; t8[2]=a.z; t8[3]=a.w; t8[4]=bq.x; t8[5]=bq.y; t8[6]=bq.z; t8[7]=bq.w;
        const float4* p4 = (const float4*)(mD_prev + w * 512 + lane * 8);
        float4 c = p4[0], d = p4[1];
        u8[0]=c.x; u8[1]=c.y; u8[2]=c.z; u8[3]=c.w; u8[4]=d.x; u8[5]=d.y; u8[6]=d.z; u8[7]=d.w;
    }
    float mx = t8[0], mn = t8[0], pmx = u8[0], pmn = u8[0];
    #pragma unroll
    for (int i = 1; i < 8; ++i) {
        mx = fmaxf(mx, t8[i]); mn = fminf(mn, t8[i]);
        pmx = fmaxf(pmx, u8[i]); pmn = fminf(pmn, u8[i]);
    }
    mx = wave_fmax(mx); mn = wave_fmin(mn);
    pmx = wave_fmax(pmx); pmn = wave_fmin(pmn);
    const float inv  = 1.0f / (mx - mn + 1e-8f);
    const float pinv = 1.0f / (pmx - pmn + 1e-8f);
    float dot = 0.0f;
    #pragma unroll
    for (int i = 0; i < 8; ++i) dot += ((u8[i] - pmn) * pinv) * ((t8[i] - mn) * inv);
    dot = wave_fsum(dot);
    if (lane == 0) att_l[w] = dot / 22.627417f;   // np.float32(sqrt(512))
    __syncthreads();
    if (tid == 0) {
        float m = att_l[0];
        #pragma unroll
        for (int p = 1; p < PPREV; ++p) m = fmaxf(m, att_l[p]);
        float e[PPREV], s = 0.0f;
        #pragma unroll
        for (int p = 0; p < PPREV; ++p) { e[p] = expf(att_l[p] - m); s += e[p]; }
        #pragma unroll
        for (int p = 0; p < PPREV; ++p) att[p] = e[p] / s;
    }
}

// ============================================================================
// z_att = lambda2 * sum_p clip(pw[p], +-150) * att[p]
// ============================================================================
__global__ __launch_bounds__(256)
void weighted_sum(const float* __restrict__ pw, const float* __restrict__ att,
                  const float* __restrict__ lam, float* __restrict__ zatt)
{
    const size_t i = ((size_t)blockIdx.x * 256 + threadIdx.x) * 4;
    const float l2 = *lam;
    float a[PPREV];
    #pragma unroll
    for (int p = 0; p < PPREV; ++p) a[p] = att[p];
    float4 acc = make_float4(0.f, 0.f, 0.f, 0.f);
    #pragma unroll
    for (int p = 0; p < PPREV; ++p) {
        float4 v = *(const float4*)(pw + (size_t)p * BATCH * DIM + i);
        v.x = fminf(fmaxf(v.x, -150.f), 150.f);
        v.y = fminf(fmaxf(v.y, -150.f), 150.f);
        v.z = fminf(fmaxf(v.z, -150.f), 150.f);
        v.w = fminf(fmaxf(v.w, -150.f), 150.f);
        acc.x += v.x * a[p]; acc.y += v.y * a[p]; acc.z += v.z * a[p]; acc.w += v.w * a[p];
    }
    acc.x *= l2; acc.y *= l2; acc.z *= l2; acc.w *= l2;
    *(float4*)(zatt + i) = acc;
}

// ============================================================================
// Final: mD2 = col-sum of partials, min-max normalize into out[0:512]
// ============================================================================
__global__ void finalize_fused(const float* __restrict__ partial, float* __restrict__ out)
{
    __shared__ float red[512];
    const int tid = threadIdx.x;
    float v = 0.0f;
    for (int i = 0; i < 64; ++i) v += partial[i * 512 + tid];
    red[tid] = v; __syncthreads();
    for (int off = 256; off > 0; off >>= 1) { if (tid < off) red[tid] = fmaxf(red[tid], red[tid+off]); __syncthreads(); }
    float mx = red[0]; __syncthreads();
    red[tid] = v; __syncthreads();
    for (int off = 256; off > 0; off >>= 1) { if (tid < off) red[tid] = fminf(red[tid], red[tid+off]); __syncthreads(); }
    float mn = red[0];
    out[tid] = (v - mn) / (mx - mn + 1e-8f);
}

// ============================================================================
extern "C" void kernel_launch(void* const* d_in, const int* in_sizes, int n_in,
                              void* d_out, int out_size, void* d_ws, size_t ws_size,
                              hipStream_t stream)
{
    const float* x   = (const float*)d_in[0];   // [4096,1024]
    const float* pw  = (const float*)d_in[1];   // [8,4096,1024]
    const float* Wd  = (const float*)d_in[2];   // [1,1024,1024]
    const float* S   = (const float*)d_in[3];   // [1,1024,1024] (numerically symmetric)
    const float* lam = (const float*)d_in[4];   // scalar
    const float* L   = (const float*)d_in[5];   // scalar
    float* out = (float*)d_out;                 // [512] ++ [4096*1024]

    float* b       = (float*)d_ws;                      // 4,194,304
    float* zatt    = b + (size_t)BATCH * DIM;           // 4,194,304
    float* pp_prev = zatt + (size_t)BATCH * DIM;        // 262,144
    float* pp_dens = pp_prev + 262144;                  // 32,768
    float* mD_prev = pp_dens + 32768;                   // 4096
    float* attw    = mD_prev + 4096;                    // 8
    float* sval1   = attw + 8;                          // 40,960
    float* sval2   = sval1 + 40960;                     // 40,960
    int*   sidx1   = (int*)(sval2 + 40960);             // 40,960 ints
    int*   sidx2   = sidx1 + 40960;                     // 40,960 ints

    float* c1   = out + 512;   // stage c1 in output z region (rewritten by loop_rows)
    float* zout = out + 512;

    const dim3 gg(DIM / 64, BATCH / 128);   // (16, 32) = 512 blocks

    gemm_f32<true,  false><<<gg, 256, 0, stream>>>(x, Wd, nullptr, b, L, BATCH, DIM, DIM);
    warmup_rows<<<BATCH, 256, 0, stream>>>(b, S, sidx1, sval1);
    sparse_density_stage1<<<64, 512, 0, stream>>>(sidx1, sval1, pp_dens);
    prev_density_stage1<<<dim3(PPREV, 64), 512, 0, stream>>>(pw, pp_prev);
    prev_density_stage2<<<PPREV, 512, 0, stream>>>(pp_prev, mD_prev);
    density2_attention<<<1, 512, 0, stream>>>(pp_dens, mD_prev, attw);
    weighted_sum<<<(BATCH * DIM) / 1024, 256, 0, stream>>>(pw, attw, lam, zatt);
    gemm_f32<false, true ><<<gg, 256, 0, stream>>>(zatt, S, b, c1, nullptr, BATCH, DIM, DIM);
    loop_rows<<<BATCH, 256, 0, stream>>>(c1, b, S, zout, sidx2, sval2);
    sparse_density_stage1<<<64, 512, 0, stream>>>(sidx2, sval2, pp_dens);
    finalize_fused<<<1, 512, 0, stream>>>(pp_dens, out);
}